// Round 11
// baseline (220.798 us; speedup 1.0000x reference)
//
#include <hip/hip_runtime.h>
#include <cstdint>

#define BB 2
#define CV 64
#define CR 20
#define EE 64
#define CO 64
#define NZ 256   // xs-zeroing blocks inside k_pre

// ---------------------------------------------------------------------------
// k_tr: v_feat (B,64,Mv) -> vt (B,Mv,64). 64x64 tile, 16KB LDS.
// Swizzle: value (c, m=4*mq+i) stored at tile[c*64 + ((mq ^ ((c>>2)&15))<<2) + i].
//  WRITE (b128): per wave c uniform-quad -> f(c) uniform; chunks mq^f bijective
//   per row -> each bank 2 words/row -> conflict-free.
//  READ (b32 x4): lane reads c=4cq+q, f(c)&7 = cq&7 covers all 8 bank-groups
//   twice per 16-lane mr-group -> 2-way (free). [r9 bug: f(c)=c&31 gave only
//   {q,q+4} -> 8-way, 2.8M conflicts]
// ---------------------------------------------------------------------------
__global__ __launch_bounds__(256) void k_tr(
    const float* __restrict__ vf, float* __restrict__ vt, int Mv, int ntm) {
  __shared__ float tile[64 * 64];
  int b = blockIdx.x / ntm, tm = blockIdx.x % ntm;
  int m0 = tm * 64;
  int t = threadIdx.x;
  const float* src = vf + (size_t)b * CV * Mv;
  float* dst = vt + (size_t)b * Mv * 64;
  if (((Mv & 3) == 0) && (m0 + 64 <= Mv)) {
    #pragma unroll
    for (int p = 0; p < 4; ++p) {
      int c = p * 16 + (t >> 4), mq = t & 15;
      float4 v = *(const float4*)&src[(size_t)c * Mv + m0 + 4 * mq];
      *(float4*)&tile[c * 64 + ((mq ^ ((c >> 2) & 15)) << 2)] = v;
    }
    __syncthreads();
    #pragma unroll
    for (int p = 0; p < 4; ++p) {
      int ml = p * 16 + (t >> 4), cq = t & 15;
      int mc = ml >> 2, mr = ml & 3;
      int ch = (mc ^ cq) << 2;           // (4cq+q)>>2 == cq for q<4
      float4 w;
      w.x = tile[(4 * cq + 0) * 64 + ch + mr];
      w.y = tile[(4 * cq + 1) * 64 + ch + mr];
      w.z = tile[(4 * cq + 2) * 64 + ch + mr];
      w.w = tile[(4 * cq + 3) * 64 + ch + mr];
      *(float4*)&dst[(size_t)(m0 + ml) * 64 + 4 * cq] = w;
    }
  } else {
    for (int p = 0; p < 16; ++p) {
      int idx = p * 256 + t;             // c*64 + ml
      int c = idx >> 6, ml = idx & 63;
      int m = m0 + ml;
      float v = (m < Mv) ? src[(size_t)c * Mv + m] : 0.f;
      tile[c * 64 + (((ml >> 2) ^ ((c >> 2) & 15)) << 2) + (ml & 3)] = v;
    }
    __syncthreads();
    for (int p = 0; p < 16; ++p) {
      int idx = p * 256 + t;             // ml*64 + c
      int ml = idx >> 6, c = idx & 63;
      int m = m0 + ml;
      if (m < Mv)
        dst[(size_t)m * 64 + c] =
            tile[c * 64 + (((ml >> 2) ^ ((c >> 2) & 15)) << 2) + (ml & 3)];
    }
  }
}

// ---------------------------------------------------------------------------
// k_pre: blocks [0, NGQ)  : gq[b][j][e] = sum_c rf[b][c][j]*G[c][e], with
//                           G = Wq^T Wk computed locally (L2-hot weights).
//        next 16          : H[o][c] = sum_e Wo[o][e]*Wv[e][c]
//        next 1           : index dtype detect (int32 vs int64)
//        next NZ          : zero xs
// 10.5 KB LDS -> 8 blocks/CU (wave-capped), vs r9's 32KB/4-block ceiling.
// ---------------------------------------------------------------------------
__global__ __launch_bounds__(256) void k_pre(
    const float* __restrict__ rf,
    const float* __restrict__ Wq, const float* __restrict__ Wk,
    const float* __restrict__ Wv, const float* __restrict__ Wo,
    const int* __restrict__ r2p,
    float* __restrict__ gq, float* __restrict__ H,
    int* __restrict__ flag, float4* __restrict__ xs4,
    int Mr, int ntj, int NGQ, int xsE4) {
  __shared__ float smem[CR * 64 + CR * 68];   // Gl + rt
  int bid = blockIdx.x, t = threadIdx.x;
  if (bid < NGQ) {
    float* Gl = smem;            // [20][64]
    float* rt = smem + CR * 64;  // [20][68] row stride 68
    for (int idx = t; idx < CR * CV; idx += 256) {
      int cr = idx / CV, cv = idx - cr * CV;
      float s = 0.f;
      #pragma unroll
      for (int e = 0; e < EE; ++e) s += Wq[e * CR + cr] * Wk[e * CV + cv];
      Gl[idx] = s;
    }
    int b = bid / ntj, tj = bid - b * ntj;
    int j0 = tj * 64;
    const float* src = rf + (size_t)b * CR * Mr;
    for (int idx = t; idx < CR * 64; idx += 256) {
      int c = idx >> 6, jl = idx & 63;
      int j = j0 + jl;
      rt[c * 68 + jl] = (j < Mr) ? src[(size_t)c * Mr + j] : 0.f;
    }
    __syncthreads();
    int ti = t & 15, tjq = t >> 4;  // e-quad 4*ti, j-quad 4*tjq
    float acc[4][4];
    #pragma unroll
    for (int a = 0; a < 4; ++a)
      #pragma unroll
      for (int q = 0; q < 4; ++q) acc[a][q] = 0.f;
    for (int c = 0; c < CR; ++c) {
      float4 gx = *(const float4*)&Gl[c * 64 + 4 * ti];
      float4 xj = *(const float4*)&rt[c * 68 + 4 * tjq];
      #pragma unroll
      for (int a = 0; a < 4; ++a) {
        float xv = (a == 0) ? xj.x : (a == 1) ? xj.y : (a == 2) ? xj.z : xj.w;
        acc[a][0] += xv * gx.x;
        acc[a][1] += xv * gx.y;
        acc[a][2] += xv * gx.z;
        acc[a][3] += xv * gx.w;
      }
    }
    #pragma unroll
    for (int a = 0; a < 4; ++a) {
      int j = j0 + 4 * tjq + a;
      if (j < Mr) {
        float4 w = make_float4(acc[a][0], acc[a][1], acc[a][2], acc[a][3]);
        *(float4*)&gq[((size_t)b * Mr + j) * 64 + 4 * ti] = w;
      }
    }
    return;
  }
  int r = bid - NGQ;
  if (r < 16) {
    int idx = r * 256 + t;  // 0..4095
    int o = idx >> 6, c = idx & 63;
    float s = 0.f;
    #pragma unroll
    for (int e = 0; e < EE; ++e) s += Wo[o * EE + e] * Wv[e * CV + c];
    H[idx] = s;
  } else if (r == 16) {
    // int64 data: every odd 32-bit word is a zero high-word. int32 data:
    // odd words are ind[:,:,1] ~ U[0,Mv) -> P(all zero over 4096 words) ~ 0.
    __shared__ int any;
    if (t == 0) any = 0;
    __syncthreads();
    int nz = 0;
    for (int i = t; i < 4096; i += 256) nz |= r2p[2 * i + 1];
    if (nz) atomicOr(&any, 1);
    __syncthreads();
    if (t == 0) *flag = (any == 0) ? 4 : 2;  // words per (.,2) entry field
  } else {
    int z = r - 17;
    float4 zz = make_float4(0.f, 0.f, 0.f, 0.f);
    for (int i = z * 256 + t; i < xsE4; i += NZ * 256) xs4[i] = zz;
  }
}

// ---------------------------------------------------------------------------
// k_main: 8 points per wave (2 per 16-lane group), one-shot grid.
// 10 outstanding dwordx4 gathers per lane; scatter via per-wave LDS slab ->
// 8 contiguous 256B 64-lane atomicAdds (4B/atomic, proven r7).
// ---------------------------------------------------------------------------
template <int WS>
__device__ __forceinline__ void load_idx(
    const int* __restrict__ r2p, const int* __restrict__ v2p,
    int p, int Nn, int N, int P,
    int& b, int& j, int& i0, int& i1, int& i2, int& i3) {
  if (p >= P) { b = 0; j = 0; i0 = i1 = i2 = i3 = 0; return; }
  b = (p >= Nn) ? 1 : 0;
  int n = p - b * Nn;
  j = r2p[((size_t)b * Nn + n) * WS];
  const int* vi = v2p + ((size_t)b * N + (size_t)n * 4) * WS;
  if (WS == 2) {
    int4 w0 = *(const int4*)vi;
    int4 w1 = *(const int4*)(vi + 4);
    i0 = w0.x; i1 = w0.z; i2 = w1.x; i3 = w1.z;
  } else {
    i0 = vi[0]; i1 = vi[1 * WS]; i2 = vi[2 * WS]; i3 = vi[3 * WS];
  }
}

__device__ __forceinline__ float gred16(float h) {
  h += __shfl_xor(h, 1);
  h += __shfl_xor(h, 2);
  h += __shfl_xor(h, 4);
  h += __shfl_xor(h, 8);
  return h;
}

__device__ __forceinline__ float4 att4(float4 q4, float4 c0, float4 c1,
                                       float4 c2, float4 c3) {
  float s0 = gred16(q4.x * c0.x + q4.y * c0.y + q4.z * c0.z + q4.w * c0.w);
  float s1 = gred16(q4.x * c1.x + q4.y * c1.y + q4.z * c1.z + q4.w * c1.w);
  float s2 = gred16(q4.x * c2.x + q4.y * c2.y + q4.z * c2.z + q4.w * c2.w);
  float s3 = gred16(q4.x * c3.x + q4.y * c3.y + q4.z * c3.z + q4.w * c3.w);
  s0 *= 0.125f; s1 *= 0.125f; s2 *= 0.125f; s3 *= 0.125f;   // 1/sqrt(64)
  float mx = fmaxf(fmaxf(s0, s1), fmaxf(s2, s3));
  float e0 = __expf(s0 - mx), e1 = __expf(s1 - mx);
  float e2 = __expf(s2 - mx), e3 = __expf(s3 - mx);
  float inv = 1.f / (e0 + e1 + e2 + e3);
  e0 *= inv; e1 *= inv; e2 *= inv; e3 *= inv;
  float4 ag;
  ag.x = e0 * c0.x + e1 * c1.x + e2 * c2.x + e3 * c3.x;
  ag.y = e0 * c0.y + e1 * c1.y + e2 * c2.y + e3 * c3.y;
  ag.z = e0 * c0.z + e1 * c1.z + e2 * c2.z + e3 * c3.z;
  ag.w = e0 * c0.w + e1 * c1.w + e2 * c2.w + e3 * c3.w;
  return ag;
}

template <int WS>
__device__ __forceinline__ void main_body(
    const float* __restrict__ vt, const float* __restrict__ gq,
    const int* __restrict__ v2p, const int* __restrict__ r2p,
    float* __restrict__ xs, float* __restrict__ my,
    int Mv, int Mr, int N, int Nn, int P) {
  int t = threadIdx.x;
  int lane = t & 63, sl = t & 15, grp = (t >> 4) & 3;
  int base = (blockIdx.x * 4 + (t >> 6)) * 8;
  if (base >= P) return;
  int pA = base + grp, pB = base + grp + 4;
  int bA, jA, a0, a1, a2, a3, bB, jB, b0, b1, b2, b3;
  load_idx<WS>(r2p, v2p, pA, Nn, N, P, bA, jA, a0, a1, a2, a3);
  load_idx<WS>(r2p, v2p, pB, Nn, N, P, bB, jB, b0, b1, b2, b3);
  const float* gqA = gq + (size_t)bA * Mr * 64;
  const float* vbA = vt + (size_t)bA * Mv * 64;
  const float* gqB = gq + (size_t)bB * Mr * 64;
  const float* vbB = vt + (size_t)bB * Mv * 64;
  float4 qA  = *(const float4*)&gqA[(size_t)jA * 64 + 4 * sl];
  float4 cA0 = *(const float4*)&vbA[(size_t)a0 * 64 + 4 * sl];
  float4 cA1 = *(const float4*)&vbA[(size_t)a1 * 64 + 4 * sl];
  float4 cA2 = *(const float4*)&vbA[(size_t)a2 * 64 + 4 * sl];
  float4 cA3 = *(const float4*)&vbA[(size_t)a3 * 64 + 4 * sl];
  float4 qB  = *(const float4*)&gqB[(size_t)jB * 64 + 4 * sl];
  float4 cB0 = *(const float4*)&vbB[(size_t)b0 * 64 + 4 * sl];
  float4 cB1 = *(const float4*)&vbB[(size_t)b1 * 64 + 4 * sl];
  float4 cB2 = *(const float4*)&vbB[(size_t)b2 * 64 + 4 * sl];
  float4 cB3 = *(const float4*)&vbB[(size_t)b3 * 64 + 4 * sl];
  float4 agA = att4(qA, cA0, cA1, cA2, cA3);
  *(float4*)&my[grp * 68 + 4 * sl] = agA;
  float4 agB = att4(qB, cB0, cB1, cB2, cB3);
  *(float4*)&my[(grp + 4) * 68 + 4 * sl] = agB;
  // Same-wave DS ordering: writes above precede reads below, no barrier.
  #pragma unroll
  for (int g = 0; g < 8; ++g) {
    if (base + g < P) {
      int jg = __shfl((g < 4) ? jA : jB, (g & 3) * 16);
      int bg = ((base + g) >= Nn) ? 1 : 0;
      float v = my[g * 68 + lane];
      atomicAdd(&xs[((size_t)bg * Mr + jg) * 64 + lane], v);  // 256B contiguous
    }
  }
}

__global__ __launch_bounds__(256, 8) void k_main(
    const float* __restrict__ vt, const float* __restrict__ gq,
    const int* __restrict__ v2p, const int* __restrict__ r2p,
    float* __restrict__ xs, const int* __restrict__ flag,
    int Mv, int Mr, int N, int Nn, int P) {
  __shared__ float sc[4 * 8 * 68];    // 4 waves x 8 rows x 68 words
  float* my = sc + (threadIdx.x >> 6) * (8 * 68);
  if (*flag == 2)
    main_body<2>(vt, gq, v2p, r2p, xs, my, Mv, Mr, N, Nn, P);
  else
    main_body<4>(vt, gq, v2p, r2p, xs, my, Mv, Mr, N, Nn, P);
}

// ---------------------------------------------------------------------------
// k_out_t: out[b][o][j] = sum_c H[o][c] * xs[b][j][c]. 64x64 tile GEMM,
// 4x4 register blocking, float4 LDS reads, XOR-swizzled H tile, LDS-staged
// float4 coalesced stores. (Proven r7.)
// ---------------------------------------------------------------------------
__device__ __forceinline__ int hsw(int fidx) {
  return fidx ^ (((fidx >> 8) & 7) << 2);
}

__global__ __launch_bounds__(256) void k_out_t(
    const float* __restrict__ xs, const float* __restrict__ H,
    float* __restrict__ out, int Mr, int ntj) {
  __shared__ float Hl[CO * CV];   // [o][c], XOR-swizzled quads
  __shared__ float xt[64][68];    // [j][c] then reused as [o][jl]
  int b = blockIdx.x / ntj, tj = blockIdx.x % ntj;
  int j0 = tj * 64;
  int t = threadIdx.x;
  for (int idx = t; idx < CO * CV; idx += 256) Hl[hsw(idx)] = H[idx];
  const float* src = xs + (size_t)b * Mr * 64;
  #pragma unroll
  for (int k = 0; k < 4; ++k) {
    int jl = k * 16 + (t >> 4), c4 = t & 15;
    int j = j0 + jl;
    float4 v = (j < Mr) ? *(const float4*)&src[(size_t)j * 64 + 4 * c4]
                        : make_float4(0.f, 0.f, 0.f, 0.f);
    *(float4*)&xt[jl][4 * c4] = v;
  }
  __syncthreads();
  int ti = t & 15;
  int tjq4 = t >> 4;
  float acc[4][4];
  #pragma unroll
  for (int a = 0; a < 4; ++a)
    #pragma unroll
    for (int q = 0; q < 4; ++q) acc[a][q] = 0.f;
  #pragma unroll 4
  for (int cq = 0; cq < 16; ++cq) {
    float4 xv[4], hb[4];
    #pragma unroll
    for (int a = 0; a < 4; ++a)
      xv[a] = *(const float4*)&xt[4 * tjq4 + a][4 * cq];
    #pragma unroll
    for (int q = 0; q < 4; ++q) {
      int row = 4 * ti + q;
      hb[q] = *(const float4*)&Hl[hsw(row * 64 + 4 * cq)];
    }
    #pragma unroll
    for (int a = 0; a < 4; ++a)
      #pragma unroll
      for (int q = 0; q < 4; ++q)
        acc[a][q] += xv[a].x * hb[q].x + xv[a].y * hb[q].y +
                     xv[a].z * hb[q].z + xv[a].w * hb[q].w;
  }
  __syncthreads();
  #pragma unroll
  for (int a = 0; a < 4; ++a)
    #pragma unroll
    for (int q = 0; q < 4; ++q)
      xt[4 * ti + q][4 * tjq4 + a] = acc[a][q];
  __syncthreads();
  float* dst = out + (size_t)b * CO * Mr;
  #pragma unroll
  for (int k = 0; k < 4; ++k) {
    int o = k * 16 + (t >> 4), j4 = t & 15;
    int j = j0 + 4 * j4;
    if (j + 3 < Mr) {
      *(float4*)&dst[(size_t)o * Mr + j] = *(const float4*)&xt[o][4 * j4];
    } else {
      #pragma unroll
      for (int i = 0; i < 4; ++i)
        if (j + i < Mr) dst[(size_t)o * Mr + j + i] = xt[o][4 * j4 + i];
    }
  }
}

// ---------------------------------------------------------------------------
extern "C" void kernel_launch(void* const* d_in, const int* in_sizes, int n_in,
                              void* d_out, int out_size, void* d_ws, size_t ws_size,
                              hipStream_t stream) {
  const float* v_feat = (const float*)d_in[0];
  const float* r_feat = (const float*)d_in[1];
  const float* Wq = (const float*)d_in[2];
  const float* Wk = (const float*)d_in[3];
  const float* Wv = (const float*)d_in[4];
  const float* Wo = (const float*)d_in[5];
  const int* v2p = (const int*)d_in[6];
  const int* r2p = (const int*)d_in[7];

  int Mv = in_sizes[0] / (BB * CV);   // 100000
  int Mr = in_sizes[1] / (BB * CR);   // 50000
  int N  = in_sizes[6] / (BB * 2);    // 262144
  int Nn = in_sizes[7] / (BB * 2);    // 65536  (bundle = 4)

  float* ws = (float*)d_ws;
  float* vt = ws;                                   // B*Mv*64   (51.2 MB)
  float* gq = vt + (size_t)BB * Mv * 64;            // B*Mr*64   (25.6 MB)
  float* xs = gq + (size_t)BB * Mr * 64;            // B*Mr*64   (25.6 MB)
  float* H  = xs + (size_t)BB * Mr * 64;            // 64*64
  int* flag = (int*)(H + CO * CV);
  float* out = (float*)d_out;

  int ntm = (Mv + 63) / 64;
  int ntj = (Mr + 63) / 64;
  int NGQ = BB * ntj;
  int xsE4 = (BB * Mr * 64) / 4;

  k_tr<<<BB * ntm, 256, 0, stream>>>(v_feat, vt, Mv, ntm);

  k_pre<<<NGQ + 17 + NZ, 256, 0, stream>>>(r_feat, Wq, Wk, Wv, Wo, r2p,
                                           gq, H, flag, (float4*)xs,
                                           Mr, ntj, NGQ, xsE4);

  int P = BB * Nn;
  int blocks = (P + 31) / 32;   // 8 pts/wave x 4 waves/block, one-shot
  k_main<<<blocks, 256, 0, stream>>>(vt, gq, v2p, r2p, xs, flag,
                                     Mv, Mr, N, Nn, P);

  k_out_t<<<BB * ntj, 256, 0, stream>>>(xs, H, out, Mr, ntj);
}

// Round 12
// 208.524 us; speedup vs baseline: 1.0589x; 1.0589x over previous
//
#include <hip/hip_runtime.h>
#include <cstdint>

#define BB 2
#define CV 64
#define CR 20
#define EE 64
#define CO 64
#define NZ 256   // xs-zeroing blocks appended to k_tr

// ---------------------------------------------------------------------------
// k_tr: blocks [0, NT)   : v_feat (B,64,Mv) -> vt (B,Mv,64) transpose
//       next 5           : G[cr][cv] = sum_e Wq[e][cr]*Wk[e][cv]  (once!)
//       next 16          : H[o][c]   = sum_e Wo[o][e]*Wv[e][c]
//       next 1           : index dtype detect (int32 vs int64)
//       next NZ          : zero xs
// Transpose: 64x64 tile, swizzle tile[c*64 + ((mq ^ ((c>>2)&15))<<2) + i]:
//  WRITE b128: chunks mq^f(c) bijective per row -> conflict-free.
//  READ b32x4: lane reads c=4cq+q; f(c)&7 = cq&7 covers all 8 bank-groups
//   twice per 16-lane group -> 2-way (free). [r9 bug: f(c)=c&31 -> 8-way]
// ---------------------------------------------------------------------------
__global__ __launch_bounds__(256) void k_tr(
    const float* __restrict__ vf, const float* __restrict__ Wq,
    const float* __restrict__ Wk, const float* __restrict__ Wv,
    const float* __restrict__ Wo, const int* __restrict__ r2p,
    float* __restrict__ vt, float* __restrict__ G, float* __restrict__ H,
    int* __restrict__ flag, float4* __restrict__ xs4,
    int Mv, int ntm, int NT, int xsE4) {
  __shared__ float tile[64 * 64];
  int bid = blockIdx.x, t = threadIdx.x;
  if (bid < NT) {
    int b = bid / ntm, tm = bid % ntm;
    int m0 = tm * 64;
    const float* src = vf + (size_t)b * CV * Mv;
    float* dst = vt + (size_t)b * Mv * 64;
    if (((Mv & 3) == 0) && (m0 + 64 <= Mv)) {
      #pragma unroll
      for (int p = 0; p < 4; ++p) {
        int c = p * 16 + (t >> 4), mq = t & 15;
        float4 v = *(const float4*)&src[(size_t)c * Mv + m0 + 4 * mq];
        *(float4*)&tile[c * 64 + ((mq ^ ((c >> 2) & 15)) << 2)] = v;
      }
      __syncthreads();
      #pragma unroll
      for (int p = 0; p < 4; ++p) {
        int ml = p * 16 + (t >> 4), cq = t & 15;
        int mc = ml >> 2, mr = ml & 3;
        int ch = (mc ^ cq) << 2;           // (4cq+q)>>2 == cq for q<4
        float4 w;
        w.x = tile[(4 * cq + 0) * 64 + ch + mr];
        w.y = tile[(4 * cq + 1) * 64 + ch + mr];
        w.z = tile[(4 * cq + 2) * 64 + ch + mr];
        w.w = tile[(4 * cq + 3) * 64 + ch + mr];
        *(float4*)&dst[(size_t)(m0 + ml) * 64 + 4 * cq] = w;
      }
    } else {
      for (int p = 0; p < 16; ++p) {
        int idx = p * 256 + t;             // c*64 + ml
        int c = idx >> 6, ml = idx & 63;
        int m = m0 + ml;
        float v = (m < Mv) ? src[(size_t)c * Mv + m] : 0.f;
        tile[c * 64 + (((ml >> 2) ^ ((c >> 2) & 15)) << 2) + (ml & 3)] = v;
      }
      __syncthreads();
      for (int p = 0; p < 16; ++p) {
        int idx = p * 256 + t;             // ml*64 + c
        int ml = idx >> 6, c = idx & 63;
        int m = m0 + ml;
        if (m < Mv)
          dst[(size_t)m * 64 + c] =
              tile[c * 64 + (((ml >> 2) ^ ((c >> 2) & 15)) << 2) + (ml & 3)];
      }
    }
    return;
  }
  int r = bid - NT;
  if (r < 5) {
    int idx = r * 256 + t;
    if (idx < CR * CV) {
      int cr = idx / CV, cv = idx - cr * CV;
      float s = 0.f;
      #pragma unroll
      for (int e = 0; e < EE; ++e) s += Wq[e * CR + cr] * Wk[e * CV + cv];
      G[idx] = s;
    }
  } else if (r < 21) {
    int idx = (r - 5) * 256 + t;  // 0..4095
    int o = idx >> 6, c = idx & 63;
    float s = 0.f;
    #pragma unroll
    for (int e = 0; e < EE; ++e) s += Wo[o * EE + e] * Wv[e * CV + c];
    H[idx] = s;
  } else if (r == 21) {
    // int64 data: every odd 32-bit word is a zero high-word. int32 data:
    // odd words are ind[:,:,1] ~ U[0,Mv) -> P(all zero over 4096 words) ~ 0.
    __shared__ int any;
    if (t == 0) any = 0;
    __syncthreads();
    int nz = 0;
    for (int i = t; i < 4096; i += 256) nz |= r2p[2 * i + 1];
    if (nz) atomicOr(&any, 1);
    __syncthreads();
    if (t == 0) *flag = (any == 0) ? 4 : 2;  // words per (.,2) entry field
  } else {
    int z = r - 22;
    float4 zz = make_float4(0.f, 0.f, 0.f, 0.f);
    for (int i = z * 256 + t; i < xsE4; i += NZ * 256) xs4[i] = zz;
  }
}

// ---------------------------------------------------------------------------
// k_gq: gq[b][j][e] = sum_c rf[b][c][j] * G[c][e]. G LOADED from global
// (L3-hot 5KB broadcast) — r11's per-block recompute cost 88 VGPR / 16% occ /
// 44 us. 4x4 register-blocked outer products; float4 LDS reads.
// ---------------------------------------------------------------------------
__global__ __launch_bounds__(256) void k_gq(
    const float* __restrict__ rf, const float* __restrict__ G,
    float* __restrict__ gq, int Mr, int ntj) {
  __shared__ float Gl[CR * 64];   // [c][e]
  __shared__ float rt[CR * 68];   // [c][jl], row stride 68
  int bid = blockIdx.x, t = threadIdx.x;
  for (int idx = t; idx < CR * CV; idx += 256) Gl[idx] = G[idx];
  int b = bid / ntj, tj = bid - b * ntj;
  int j0 = tj * 64;
  const float* src = rf + (size_t)b * CR * Mr;
  for (int idx = t; idx < CR * 64; idx += 256) {
    int c = idx >> 6, jl = idx & 63;
    int j = j0 + jl;
    rt[c * 68 + jl] = (j < Mr) ? src[(size_t)c * Mr + j] : 0.f;
  }
  __syncthreads();
  int ti = t & 15, tjq = t >> 4;  // e-quad 4*ti, j-quad 4*tjq
  float acc[4][4];
  #pragma unroll
  for (int a = 0; a < 4; ++a)
    #pragma unroll
    for (int q = 0; q < 4; ++q) acc[a][q] = 0.f;
  for (int c = 0; c < CR; ++c) {
    float4 gx = *(const float4*)&Gl[c * 64 + 4 * ti];
    float4 xj = *(const float4*)&rt[c * 68 + 4 * tjq];
    #pragma unroll
    for (int a = 0; a < 4; ++a) {
      float xv = (a == 0) ? xj.x : (a == 1) ? xj.y : (a == 2) ? xj.z : xj.w;
      acc[a][0] += xv * gx.x;
      acc[a][1] += xv * gx.y;
      acc[a][2] += xv * gx.z;
      acc[a][3] += xv * gx.w;
    }
  }
  #pragma unroll
  for (int a = 0; a < 4; ++a) {
    int j = j0 + 4 * tjq + a;
    if (j < Mr) {
      float4 w = make_float4(acc[a][0], acc[a][1], acc[a][2], acc[a][3]);
      *(float4*)&gq[((size_t)b * Mr + j) * 64 + 4 * ti] = w;
    }
  }
}

// ---------------------------------------------------------------------------
// k_main: 8 points per wave (2 per 16-lane group), one-shot grid.
// 10 outstanding dwordx4 gathers per lane; scatter via per-wave LDS slab ->
// 8 contiguous 256B 64-lane atomicAdds (4B/atomic, proven r7).
// ---------------------------------------------------------------------------
template <int WS>
__device__ __forceinline__ void load_idx(
    const int* __restrict__ r2p, const int* __restrict__ v2p,
    int p, int Nn, int N, int P,
    int& b, int& j, int& i0, int& i1, int& i2, int& i3) {
  if (p >= P) { b = 0; j = 0; i0 = i1 = i2 = i3 = 0; return; }
  b = (p >= Nn) ? 1 : 0;
  int n = p - b * Nn;
  j = r2p[((size_t)b * Nn + n) * WS];
  const int* vi = v2p + ((size_t)b * N + (size_t)n * 4) * WS;
  if (WS == 2) {
    int4 w0 = *(const int4*)vi;
    int4 w1 = *(const int4*)(vi + 4);
    i0 = w0.x; i1 = w0.z; i2 = w1.x; i3 = w1.z;
  } else {
    i0 = vi[0]; i1 = vi[1 * WS]; i2 = vi[2 * WS]; i3 = vi[3 * WS];
  }
}

__device__ __forceinline__ float gred16(float h) {
  h += __shfl_xor(h, 1);
  h += __shfl_xor(h, 2);
  h += __shfl_xor(h, 4);
  h += __shfl_xor(h, 8);
  return h;
}

__device__ __forceinline__ float4 att4(float4 q4, float4 c0, float4 c1,
                                       float4 c2, float4 c3) {
  float s0 = gred16(q4.x * c0.x + q4.y * c0.y + q4.z * c0.z + q4.w * c0.w);
  float s1 = gred16(q4.x * c1.x + q4.y * c1.y + q4.z * c1.z + q4.w * c1.w);
  float s2 = gred16(q4.x * c2.x + q4.y * c2.y + q4.z * c2.z + q4.w * c2.w);
  float s3 = gred16(q4.x * c3.x + q4.y * c3.y + q4.z * c3.z + q4.w * c3.w);
  s0 *= 0.125f; s1 *= 0.125f; s2 *= 0.125f; s3 *= 0.125f;   // 1/sqrt(64)
  float mx = fmaxf(fmaxf(s0, s1), fmaxf(s2, s3));
  float e0 = __expf(s0 - mx), e1 = __expf(s1 - mx);
  float e2 = __expf(s2 - mx), e3 = __expf(s3 - mx);
  float inv = 1.f / (e0 + e1 + e2 + e3);
  e0 *= inv; e1 *= inv; e2 *= inv; e3 *= inv;
  float4 ag;
  ag.x = e0 * c0.x + e1 * c1.x + e2 * c2.x + e3 * c3.x;
  ag.y = e0 * c0.y + e1 * c1.y + e2 * c2.y + e3 * c3.y;
  ag.z = e0 * c0.z + e1 * c1.z + e2 * c2.z + e3 * c3.z;
  ag.w = e0 * c0.w + e1 * c1.w + e2 * c2.w + e3 * c3.w;
  return ag;
}

template <int WS>
__device__ __forceinline__ void main_body(
    const float* __restrict__ vt, const float* __restrict__ gq,
    const int* __restrict__ v2p, const int* __restrict__ r2p,
    float* __restrict__ xs, float* __restrict__ my,
    int Mv, int Mr, int N, int Nn, int P) {
  int t = threadIdx.x;
  int lane = t & 63, sl = t & 15, grp = (t >> 4) & 3;
  int base = (blockIdx.x * 4 + (t >> 6)) * 8;
  if (base >= P) return;
  int pA = base + grp, pB = base + grp + 4;
  int bA, jA, a0, a1, a2, a3, bB, jB, b0, b1, b2, b3;
  load_idx<WS>(r2p, v2p, pA, Nn, N, P, bA, jA, a0, a1, a2, a3);
  load_idx<WS>(r2p, v2p, pB, Nn, N, P, bB, jB, b0, b1, b2, b3);
  const float* gqA = gq + (size_t)bA * Mr * 64;
  const float* vbA = vt + (size_t)bA * Mv * 64;
  const float* gqB = gq + (size_t)bB * Mr * 64;
  const float* vbB = vt + (size_t)bB * Mv * 64;
  float4 qA  = *(const float4*)&gqA[(size_t)jA * 64 + 4 * sl];
  float4 cA0 = *(const float4*)&vbA[(size_t)a0 * 64 + 4 * sl];
  float4 cA1 = *(const float4*)&vbA[(size_t)a1 * 64 + 4 * sl];
  float4 cA2 = *(const float4*)&vbA[(size_t)a2 * 64 + 4 * sl];
  float4 cA3 = *(const float4*)&vbA[(size_t)a3 * 64 + 4 * sl];
  float4 qB  = *(const float4*)&gqB[(size_t)jB * 64 + 4 * sl];
  float4 cB0 = *(const float4*)&vbB[(size_t)b0 * 64 + 4 * sl];
  float4 cB1 = *(const float4*)&vbB[(size_t)b1 * 64 + 4 * sl];
  float4 cB2 = *(const float4*)&vbB[(size_t)b2 * 64 + 4 * sl];
  float4 cB3 = *(const float4*)&vbB[(size_t)b3 * 64 + 4 * sl];
  float4 agA = att4(qA, cA0, cA1, cA2, cA3);
  *(float4*)&my[grp * 68 + 4 * sl] = agA;
  float4 agB = att4(qB, cB0, cB1, cB2, cB3);
  *(float4*)&my[(grp + 4) * 68 + 4 * sl] = agB;
  // Same-wave DS ordering: writes above precede reads below, no barrier.
  #pragma unroll
  for (int g = 0; g < 8; ++g) {
    if (base + g < P) {
      int jg = __shfl((g < 4) ? jA : jB, (g & 3) * 16);
      int bg = ((base + g) >= Nn) ? 1 : 0;
      float v = my[g * 68 + lane];
      atomicAdd(&xs[((size_t)bg * Mr + jg) * 64 + lane], v);  // 256B contiguous
    }
  }
}

__global__ __launch_bounds__(256, 8) void k_main(
    const float* __restrict__ vt, const float* __restrict__ gq,
    const int* __restrict__ v2p, const int* __restrict__ r2p,
    float* __restrict__ xs, const int* __restrict__ flag,
    int Mv, int Mr, int N, int Nn, int P) {
  __shared__ float sc[4 * 8 * 68];    // 4 waves x 8 rows x 68 words
  float* my = sc + (threadIdx.x >> 6) * (8 * 68);
  if (*flag == 2)
    main_body<2>(vt, gq, v2p, r2p, xs, my, Mv, Mr, N, Nn, P);
  else
    main_body<4>(vt, gq, v2p, r2p, xs, my, Mv, Mr, N, Nn, P);
}

// ---------------------------------------------------------------------------
// k_out_t: out[b][o][j] = sum_c H[o][c] * xs[b][j][c]. 64x64 tile GEMM,
// 4x4 register blocking, float4 LDS reads, XOR-swizzled H tile, LDS-staged
// float4 coalesced stores. (Proven r7.)
// ---------------------------------------------------------------------------
__device__ __forceinline__ int hsw(int fidx) {
  return fidx ^ (((fidx >> 8) & 7) << 2);
}

__global__ __launch_bounds__(256) void k_out_t(
    const float* __restrict__ xs, const float* __restrict__ H,
    float* __restrict__ out, int Mr, int ntj) {
  __shared__ float Hl[CO * CV];   // [o][c], XOR-swizzled quads
  __shared__ float xt[64][68];    // [j][c] then reused as [o][jl]
  int b = blockIdx.x / ntj, tj = blockIdx.x % ntj;
  int j0 = tj * 64;
  int t = threadIdx.x;
  for (int idx = t; idx < CO * CV; idx += 256) Hl[hsw(idx)] = H[idx];
  const float* src = xs + (size_t)b * Mr * 64;
  #pragma unroll
  for (int k = 0; k < 4; ++k) {
    int jl = k * 16 + (t >> 4), c4 = t & 15;
    int j = j0 + jl;
    float4 v = (j < Mr) ? *(const float4*)&src[(size_t)j * 64 + 4 * c4]
                        : make_float4(0.f, 0.f, 0.f, 0.f);
    *(float4*)&xt[jl][4 * c4] = v;
  }
  __syncthreads();
  int ti = t & 15;
  int tjq4 = t >> 4;
  float acc[4][4];
  #pragma unroll
  for (int a = 0; a < 4; ++a)
    #pragma unroll
    for (int q = 0; q < 4; ++q) acc[a][q] = 0.f;
  #pragma unroll 4
  for (int cq = 0; cq < 16; ++cq) {
    float4 xv[4], hb[4];
    #pragma unroll
    for (int a = 0; a < 4; ++a)
      xv[a] = *(const float4*)&xt[4 * tjq4 + a][4 * cq];
    #pragma unroll
    for (int q = 0; q < 4; ++q) {
      int row = 4 * ti + q;
      hb[q] = *(const float4*)&Hl[hsw(row * 64 + 4 * cq)];
    }
    #pragma unroll
    for (int a = 0; a < 4; ++a)
      #pragma unroll
      for (int q = 0; q < 4; ++q)
        acc[a][q] += xv[a].x * hb[q].x + xv[a].y * hb[q].y +
                     xv[a].z * hb[q].z + xv[a].w * hb[q].w;
  }
  __syncthreads();
  #pragma unroll
  for (int a = 0; a < 4; ++a)
    #pragma unroll
    for (int q = 0; q < 4; ++q)
      xt[4 * ti + q][4 * tjq4 + a] = acc[a][q];
  __syncthreads();
  float* dst = out + (size_t)b * CO * Mr;
  #pragma unroll
  for (int k = 0; k < 4; ++k) {
    int o = k * 16 + (t >> 4), j4 = t & 15;
    int j = j0 + 4 * j4;
    if (j + 3 < Mr) {
      *(float4*)&dst[(size_t)o * Mr + j] = *(const float4*)&xt[o][4 * j4];
    } else {
      #pragma unroll
      for (int i = 0; i < 4; ++i)
        if (j + i < Mr) dst[(size_t)o * Mr + j + i] = xt[o][4 * j4 + i];
    }
  }
}

// ---------------------------------------------------------------------------
extern "C" void kernel_launch(void* const* d_in, const int* in_sizes, int n_in,
                              void* d_out, int out_size, void* d_ws, size_t ws_size,
                              hipStream_t stream) {
  const float* v_feat = (const float*)d_in[0];
  const float* r_feat = (const float*)d_in[1];
  const float* Wq = (const float*)d_in[2];
  const float* Wk = (const float*)d_in[3];
  const float* Wv = (const float*)d_in[4];
  const float* Wo = (const float*)d_in[5];
  const int* v2p = (const int*)d_in[6];
  const int* r2p = (const int*)d_in[7];

  int Mv = in_sizes[0] / (BB * CV);   // 100000
  int Mr = in_sizes[1] / (BB * CR);   // 50000
  int N  = in_sizes[6] / (BB * 2);    // 262144
  int Nn = in_sizes[7] / (BB * 2);    // 65536  (bundle = 4)

  float* ws = (float*)d_ws;
  float* vt = ws;                                   // B*Mv*64   (51.2 MB)
  float* gq = vt + (size_t)BB * Mv * 64;            // B*Mr*64   (25.6 MB)
  float* xs = gq + (size_t)BB * Mr * 64;            // B*Mr*64   (25.6 MB)
  float* G  = xs + (size_t)BB * Mr * 64;            // 20*64
  float* H  = G + CR * CV;                          // 64*64
  int* flag = (int*)(H + CO * CV);
  float* out = (float*)d_out;

  int ntm = (Mv + 63) / 64;
  int ntj = (Mr + 63) / 64;
  int NT = BB * ntm;
  int NGQ = BB * ntj;
  int xsE4 = (BB * Mr * 64) / 4;

  k_tr<<<NT + 22 + NZ, 256, 0, stream>>>(v_feat, Wq, Wk, Wv, Wo, r2p,
                                         vt, G, H, flag, (float4*)xs,
                                         Mv, ntm, NT, xsE4);

  k_gq<<<NGQ, 256, 0, stream>>>(r_feat, G, gq, Mr, ntj);

  int P = BB * Nn;
  int blocks = (P + 31) / 32;   // 8 pts/wave x 4 waves/block, one-shot
  k_main<<<blocks, 256, 0, stream>>>(vt, gq, v2p, r2p, xs, flag,
                                     Mv, Mr, N, Nn, P);

  k_out_t<<<BB * ntj, 256, 0, stream>>>(xs, H, out, Mr, ntj);
}

// Round 13
// 208.522 us; speedup vs baseline: 1.0589x; 1.0000x over previous
//
#include <hip/hip_runtime.h>
#include <cstdint>

#define BB 2
#define CV 64
#define CR 20
#define EE 64
#define CO 64
#define NZ 256   // xs-zeroing blocks appended to k_tr

// ---------------------------------------------------------------------------
// k_tr: blocks [0, NT)   : v_feat (B,64,Mv) -> vt (B,Mv,64) transpose
//       next 5           : G[cr][cv] = sum_e Wq[e][cr]*Wk[e][cv]  (once)
//       next 16          : H[o][c]   = sum_e Wo[o][e]*Wv[e][c]
//       next 1           : index dtype detect (int32 vs int64)
//       next NZ          : zero xs
// Transpose: 64x64 tile, swizzle tile[c*64 + ((mq ^ ((c>>2)&15))<<2) + i]:
//  WRITE b128: chunks mq^f(c) bijective per row -> conflict-free.
//  READ b32x4: lane reads c=4cq+q; f(c)&7 = cq&7 covers all 8 bank-groups
//   twice per 16-lane group -> 2-way (free).
// ---------------------------------------------------------------------------
__global__ __launch_bounds__(256) void k_tr(
    const float* __restrict__ vf, const float* __restrict__ Wq,
    const float* __restrict__ Wk, const float* __restrict__ Wv,
    const float* __restrict__ Wo, const int* __restrict__ r2p,
    float* __restrict__ vt, float* __restrict__ G, float* __restrict__ H,
    int* __restrict__ flag, float4* __restrict__ xs4,
    int Mv, int ntm, int NT, int xsE4) {
  __shared__ float tile[64 * 64];
  int bid = blockIdx.x, t = threadIdx.x;
  if (bid < NT) {
    int b = bid / ntm, tm = bid % ntm;
    int m0 = tm * 64;
    const float* src = vf + (size_t)b * CV * Mv;
    float* dst = vt + (size_t)b * Mv * 64;
    if (((Mv & 3) == 0) && (m0 + 64 <= Mv)) {
      #pragma unroll
      for (int p = 0; p < 4; ++p) {
        int c = p * 16 + (t >> 4), mq = t & 15;
        float4 v = *(const float4*)&src[(size_t)c * Mv + m0 + 4 * mq];
        *(float4*)&tile[c * 64 + ((mq ^ ((c >> 2) & 15)) << 2)] = v;
      }
      __syncthreads();
      #pragma unroll
      for (int p = 0; p < 4; ++p) {
        int ml = p * 16 + (t >> 4), cq = t & 15;
        int mc = ml >> 2, mr = ml & 3;
        int ch = (mc ^ cq) << 2;           // (4cq+q)>>2 == cq for q<4
        float4 w;
        w.x = tile[(4 * cq + 0) * 64 + ch + mr];
        w.y = tile[(4 * cq + 1) * 64 + ch + mr];
        w.z = tile[(4 * cq + 2) * 64 + ch + mr];
        w.w = tile[(4 * cq + 3) * 64 + ch + mr];
        *(float4*)&dst[(size_t)(m0 + ml) * 64 + 4 * cq] = w;
      }
    } else {
      for (int p = 0; p < 16; ++p) {
        int idx = p * 256 + t;             // c*64 + ml
        int c = idx >> 6, ml = idx & 63;
        int m = m0 + ml;
        float v = (m < Mv) ? src[(size_t)c * Mv + m] : 0.f;
        tile[c * 64 + (((ml >> 2) ^ ((c >> 2) & 15)) << 2) + (ml & 3)] = v;
      }
      __syncthreads();
      for (int p = 0; p < 16; ++p) {
        int idx = p * 256 + t;             // ml*64 + c
        int ml = idx >> 6, c = idx & 63;
        int m = m0 + ml;
        if (m < Mv)
          dst[(size_t)m * 64 + c] =
              tile[c * 64 + (((ml >> 2) ^ ((c >> 2) & 15)) << 2) + (ml & 3)];
      }
    }
    return;
  }
  int r = bid - NT;
  if (r < 5) {
    int idx = r * 256 + t;
    if (idx < CR * CV) {
      int cr = idx / CV, cv = idx - cr * CV;
      float s = 0.f;
      #pragma unroll
      for (int e = 0; e < EE; ++e) s += Wq[e * CR + cr] * Wk[e * CV + cv];
      G[idx] = s;
    }
  } else if (r < 21) {
    int idx = (r - 5) * 256 + t;  // 0..4095
    int o = idx >> 6, c = idx & 63;
    float s = 0.f;
    #pragma unroll
    for (int e = 0; e < EE; ++e) s += Wo[o * EE + e] * Wv[e * CV + c];
    H[idx] = s;
  } else if (r == 21) {
    // int64 data: every odd 32-bit word is a zero high-word. int32 data:
    // odd words are ind[:,:,1] ~ U[0,Mv) -> P(all zero over 4096 words) ~ 0.
    __shared__ int any;
    if (t == 0) any = 0;
    __syncthreads();
    int nz = 0;
    for (int i = t; i < 4096; i += 256) nz |= r2p[2 * i + 1];
    if (nz) atomicOr(&any, 1);
    __syncthreads();
    if (t == 0) *flag = (any == 0) ? 4 : 2;  // words per (.,2) entry field
  } else {
    int z = r - 22;
    float4 zz = make_float4(0.f, 0.f, 0.f, 0.f);
    for (int i = z * 256 + t; i < xsE4; i += NZ * 256) xs4[i] = zz;
  }
}

// ---------------------------------------------------------------------------
// k_gq: gq[b][j][e] = sum_c rf[b][c][j] * G[c][e]. G loaded from global
// (L3-hot 5KB broadcast). 4x4 register-blocked outer products.
// ---------------------------------------------------------------------------
__global__ __launch_bounds__(256) void k_gq(
    const float* __restrict__ rf, const float* __restrict__ G,
    float* __restrict__ gq, int Mr, int ntj) {
  __shared__ float Gl[CR * 64];   // [c][e]
  __shared__ float rt[CR * 68];   // [c][jl], row stride 68
  int bid = blockIdx.x, t = threadIdx.x;
  for (int idx = t; idx < CR * CV; idx += 256) Gl[idx] = G[idx];
  int b = bid / ntj, tj = bid - b * ntj;
  int j0 = tj * 64;
  const float* src = rf + (size_t)b * CR * Mr;
  for (int idx = t; idx < CR * 64; idx += 256) {
    int c = idx >> 6, jl = idx & 63;
    int j = j0 + jl;
    rt[c * 68 + jl] = (j < Mr) ? src[(size_t)c * Mr + j] : 0.f;
  }
  __syncthreads();
  int ti = t & 15, tjq = t >> 4;  // e-quad 4*ti, j-quad 4*tjq
  float acc[4][4];
  #pragma unroll
  for (int a = 0; a < 4; ++a)
    #pragma unroll
    for (int q = 0; q < 4; ++q) acc[a][q] = 0.f;
  for (int c = 0; c < CR; ++c) {
    float4 gx = *(const float4*)&Gl[c * 64 + 4 * ti];
    float4 xj = *(const float4*)&rt[c * 68 + 4 * tjq];
    #pragma unroll
    for (int a = 0; a < 4; ++a) {
      float xv = (a == 0) ? xj.x : (a == 1) ? xj.y : (a == 2) ? xj.z : xj.w;
      acc[a][0] += xv * gx.x;
      acc[a][1] += xv * gx.y;
      acc[a][2] += xv * gx.z;
      acc[a][3] += xv * gx.w;
    }
  }
  #pragma unroll
  for (int a = 0; a < 4; ++a) {
    int j = j0 + 4 * tjq + a;
    if (j < Mr) {
      float4 w = make_float4(acc[a][0], acc[a][1], acc[a][2], acc[a][3]);
      *(float4*)&gq[((size_t)b * Mr + j) * 64 + 4 * ti] = w;
    }
  }
}

// ---------------------------------------------------------------------------
// k_main: 16 points per wave = 2 loop iterations x 8 points (2 per 16-lane
// group). The loop lets iteration-0's fire-and-forget atomics overlap
// iteration-1's index loads + gathers; only the last iteration pays the
// end-of-wave vmcnt drain (r12's one-shot paid it every 8 points).
// Scatter via per-wave LDS slab -> contiguous 256B 64-lane atomicAdds
// (4B/atomic HBM accounting, proven r7). LDS WAR across iterations is safe
// by same-wave DS program ordering.
// ---------------------------------------------------------------------------
template <int WS>
__device__ __forceinline__ void load_idx(
    const int* __restrict__ r2p, const int* __restrict__ v2p,
    int p, int Nn, int N, int P,
    int& b, int& j, int& i0, int& i1, int& i2, int& i3) {
  if (p >= P) { b = 0; j = 0; i0 = i1 = i2 = i3 = 0; return; }
  b = (p >= Nn) ? 1 : 0;
  int n = p - b * Nn;
  j = r2p[((size_t)b * Nn + n) * WS];
  const int* vi = v2p + ((size_t)b * N + (size_t)n * 4) * WS;
  if (WS == 2) {
    int4 w0 = *(const int4*)vi;
    int4 w1 = *(const int4*)(vi + 4);
    i0 = w0.x; i1 = w0.z; i2 = w1.x; i3 = w1.z;
  } else {
    i0 = vi[0]; i1 = vi[1 * WS]; i2 = vi[2 * WS]; i3 = vi[3 * WS];
  }
}

__device__ __forceinline__ float gred16(float h) {
  h += __shfl_xor(h, 1);
  h += __shfl_xor(h, 2);
  h += __shfl_xor(h, 4);
  h += __shfl_xor(h, 8);
  return h;
}

__device__ __forceinline__ float4 att4(float4 q4, float4 c0, float4 c1,
                                       float4 c2, float4 c3) {
  float s0 = gred16(q4.x * c0.x + q4.y * c0.y + q4.z * c0.z + q4.w * c0.w);
  float s1 = gred16(q4.x * c1.x + q4.y * c1.y + q4.z * c1.z + q4.w * c1.w);
  float s2 = gred16(q4.x * c2.x + q4.y * c2.y + q4.z * c2.z + q4.w * c2.w);
  float s3 = gred16(q4.x * c3.x + q4.y * c3.y + q4.z * c3.z + q4.w * c3.w);
  s0 *= 0.125f; s1 *= 0.125f; s2 *= 0.125f; s3 *= 0.125f;   // 1/sqrt(64)
  float mx = fmaxf(fmaxf(s0, s1), fmaxf(s2, s3));
  float e0 = __expf(s0 - mx), e1 = __expf(s1 - mx);
  float e2 = __expf(s2 - mx), e3 = __expf(s3 - mx);
  float inv = 1.f / (e0 + e1 + e2 + e3);
  e0 *= inv; e1 *= inv; e2 *= inv; e3 *= inv;
  float4 ag;
  ag.x = e0 * c0.x + e1 * c1.x + e2 * c2.x + e3 * c3.x;
  ag.y = e0 * c0.y + e1 * c1.y + e2 * c2.y + e3 * c3.y;
  ag.z = e0 * c0.z + e1 * c1.z + e2 * c2.z + e3 * c3.z;
  ag.w = e0 * c0.w + e1 * c1.w + e2 * c2.w + e3 * c3.w;
  return ag;
}

template <int WS>
__device__ __forceinline__ void main_body(
    const float* __restrict__ vt, const float* __restrict__ gq,
    const int* __restrict__ v2p, const int* __restrict__ r2p,
    float* __restrict__ xs, float* __restrict__ my,
    int Mv, int Mr, int N, int Nn, int P) {
  int t = threadIdx.x;
  int lane = t & 63, sl = t & 15, grp = (t >> 4) & 3;
  int base0 = (blockIdx.x * 4 + (t >> 6)) * 16;
  if (base0 >= P) return;
  #pragma unroll
  for (int it = 0; it < 2; ++it) {
    int base = base0 + it * 8;
    if (base >= P) break;
    int pA = base + grp, pB = base + grp + 4;
    int bA, jA, a0, a1, a2, a3, bB, jB, b0, b1, b2, b3;
    load_idx<WS>(r2p, v2p, pA, Nn, N, P, bA, jA, a0, a1, a2, a3);
    load_idx<WS>(r2p, v2p, pB, Nn, N, P, bB, jB, b0, b1, b2, b3);
    const float* gqA = gq + (size_t)bA * Mr * 64;
    const float* vbA = vt + (size_t)bA * Mv * 64;
    const float* gqB = gq + (size_t)bB * Mr * 64;
    const float* vbB = vt + (size_t)bB * Mv * 64;
    float4 qA  = *(const float4*)&gqA[(size_t)jA * 64 + 4 * sl];
    float4 cA0 = *(const float4*)&vbA[(size_t)a0 * 64 + 4 * sl];
    float4 cA1 = *(const float4*)&vbA[(size_t)a1 * 64 + 4 * sl];
    float4 cA2 = *(const float4*)&vbA[(size_t)a2 * 64 + 4 * sl];
    float4 cA3 = *(const float4*)&vbA[(size_t)a3 * 64 + 4 * sl];
    float4 qB  = *(const float4*)&gqB[(size_t)jB * 64 + 4 * sl];
    float4 cB0 = *(const float4*)&vbB[(size_t)b0 * 64 + 4 * sl];
    float4 cB1 = *(const float4*)&vbB[(size_t)b1 * 64 + 4 * sl];
    float4 cB2 = *(const float4*)&vbB[(size_t)b2 * 64 + 4 * sl];
    float4 cB3 = *(const float4*)&vbB[(size_t)b3 * 64 + 4 * sl];
    float4 agA = att4(qA, cA0, cA1, cA2, cA3);
    *(float4*)&my[grp * 68 + 4 * sl] = agA;
    float4 agB = att4(qB, cB0, cB1, cB2, cB3);
    *(float4*)&my[(grp + 4) * 68 + 4 * sl] = agB;
    // Same-wave DS ordering: writes above precede reads below, no barrier.
    #pragma unroll
    for (int g = 0; g < 8; ++g) {
      if (base + g < P) {
        int jg = __shfl((g < 4) ? jA : jB, (g & 3) * 16);
        int bg = ((base + g) >= Nn) ? 1 : 0;
        float v = my[g * 68 + lane];
        atomicAdd(&xs[((size_t)bg * Mr + jg) * 64 + lane], v);  // 256B contig
      }
    }
  }
}

__global__ __launch_bounds__(256, 8) void k_main(
    const float* __restrict__ vt, const float* __restrict__ gq,
    const int* __restrict__ v2p, const int* __restrict__ r2p,
    float* __restrict__ xs, const int* __restrict__ flag,
    int Mv, int Mr, int N, int Nn, int P) {
  __shared__ float sc[4 * 8 * 68];    // 4 waves x 8 rows x 68 words
  float* my = sc + (threadIdx.x >> 6) * (8 * 68);
  if (*flag == 2)
    main_body<2>(vt, gq, v2p, r2p, xs, my, Mv, Mr, N, Nn, P);
  else
    main_body<4>(vt, gq, v2p, r2p, xs, my, Mv, Mr, N, Nn, P);
}

// ---------------------------------------------------------------------------
// k_out_t: out[b][o][j] = sum_c H[o][c] * xs[b][j][c]. 64x64 tile GEMM,
// 4x4 register blocking, float4 LDS reads, XOR-swizzled H tile, LDS-staged
// float4 coalesced stores. (Proven r7.)
// ---------------------------------------------------------------------------
__device__ __forceinline__ int hsw(int fidx) {
  return fidx ^ (((fidx >> 8) & 7) << 2);
}

__global__ __launch_bounds__(256) void k_out_t(
    const float* __restrict__ xs, const float* __restrict__ H,
    float* __restrict__ out, int Mr, int ntj) {
  __shared__ float Hl[CO * CV];   // [o][c], XOR-swizzled quads
  __shared__ float xt[64][68];    // [j][c] then reused as [o][jl]
  int b = blockIdx.x / ntj, tj = blockIdx.x % ntj;
  int j0 = tj * 64;
  int t = threadIdx.x;
  for (int idx = t; idx < CO * CV; idx += 256) Hl[hsw(idx)] = H[idx];
  const float* src = xs + (size_t)b * Mr * 64;
  #pragma unroll
  for (int k = 0; k < 4; ++k) {
    int jl = k * 16 + (t >> 4), c4 = t & 15;
    int j = j0 + jl;
    float4 v = (j < Mr) ? *(const float4*)&src[(size_t)j * 64 + 4 * c4]
                        : make_float4(0.f, 0.f, 0.f, 0.f);
    *(float4*)&xt[jl][4 * c4] = v;
  }
  __syncthreads();
  int ti = t & 15;
  int tjq4 = t >> 4;
  float acc[4][4];
  #pragma unroll
  for (int a = 0; a < 4; ++a)
    #pragma unroll
    for (int q = 0; q < 4; ++q) acc[a][q] = 0.f;
  #pragma unroll 4
  for (int cq = 0; cq < 16; ++cq) {
    float4 xv[4], hb[4];
    #pragma unroll
    for (int a = 0; a < 4; ++a)
      xv[a] = *(const float4*)&xt[4 * tjq4 + a][4 * cq];
    #pragma unroll
    for (int q = 0; q < 4; ++q) {
      int row = 4 * ti + q;
      hb[q] = *(const float4*)&Hl[hsw(row * 64 + 4 * cq)];
    }
    #pragma unroll
    for (int a = 0; a < 4; ++a)
      #pragma unroll
      for (int q = 0; q < 4; ++q)
        acc[a][q] += xv[a].x * hb[q].x + xv[a].y * hb[q].y +
                     xv[a].z * hb[q].z + xv[a].w * hb[q].w;
  }
  __syncthreads();
  #pragma unroll
  for (int a = 0; a < 4; ++a)
    #pragma unroll
    for (int q = 0; q < 4; ++q)
      xt[4 * ti + q][4 * tjq4 + a] = acc[a][q];
  __syncthreads();
  float* dst = out + (size_t)b * CO * Mr;
  #pragma unroll
  for (int k = 0; k < 4; ++k) {
    int o = k * 16 + (t >> 4), j4 = t & 15;
    int j = j0 + 4 * j4;
    if (j + 3 < Mr) {
      *(float4*)&dst[(size_t)o * Mr + j] = *(const float4*)&xt[o][4 * j4];
    } else {
      #pragma unroll
      for (int i = 0; i < 4; ++i)
        if (j + i < Mr) dst[(size_t)o * Mr + j + i] = xt[o][4 * j4 + i];
    }
  }
}

// ---------------------------------------------------------------------------
extern "C" void kernel_launch(void* const* d_in, const int* in_sizes, int n_in,
                              void* d_out, int out_size, void* d_ws, size_t ws_size,
                              hipStream_t stream) {
  const float* v_feat = (const float*)d_in[0];
  const float* r_feat = (const float*)d_in[1];
  const float* Wq = (const float*)d_in[2];
  const float* Wk = (const float*)d_in[3];
  const float* Wv = (const float*)d_in[4];
  const float* Wo = (const float*)d_in[5];
  const int* v2p = (const int*)d_in[6];
  const int* r2p = (const int*)d_in[7];

  int Mv = in_sizes[0] / (BB * CV);   // 100000
  int Mr = in_sizes[1] / (BB * CR);   // 50000
  int N  = in_sizes[6] / (BB * 2);    // 262144
  int Nn = in_sizes[7] / (BB * 2);    // 65536  (bundle = 4)

  float* ws = (float*)d_ws;
  float* vt = ws;                                   // B*Mv*64   (51.2 MB)
  float* gq = vt + (size_t)BB * Mv * 64;            // B*Mr*64   (25.6 MB)
  float* xs = gq + (size_t)BB * Mr * 64;            // B*Mr*64   (25.6 MB)
  float* G  = xs + (size_t)BB * Mr * 64;            // 20*64
  float* H  = G + CR * CV;                          // 64*64
  int* flag = (int*)(H + CO * CV);
  float* out = (float*)d_out;

  int ntm = (Mv + 63) / 64;
  int ntj = (Mr + 63) / 64;
  int NT = BB * ntm;
  int NGQ = BB * ntj;
  int xsE4 = (BB * Mr * 64) / 4;

  k_tr<<<NT + 22 + NZ, 256, 0, stream>>>(v_feat, Wq, Wk, Wv, Wo, r2p,
                                         vt, G, H, flag, (float4*)xs,
                                         Mv, ntm, NT, xsE4);

  k_gq<<<NGQ, 256, 0, stream>>>(r_feat, G, gq, Mr, ntj);

  int P = BB * Nn;
  int blocks = (P + 63) / 64;   // 16 pts/wave x 4 waves/block, 2-iter loop
  k_main<<<blocks, 256, 0, stream>>>(vt, gq, v2p, r2p, xs, flag,
                                     Mv, Mr, N, Nn, P);

  k_out_t<<<BB * ntj, 256, 0, stream>>>(xs, H, out, Mr, ntj);
}